// Round 5
// baseline (1247.790 us; speedup 1.0000x reference)
//
#include <hip/hip_runtime.h>
#include <cstdint>

#define NB 2
#define NPER 65536
#define NPTS (NB*NPER)
#define CDIM 128
#define SV 64
#define VOX (SV*SV*SV)
#define WCOLS 1217
#define WSTRIDE 1232   // padded row stride (multiple of 16 floats -> 64B-aligned rows)

// Padded Wh3 lives in a static device buffer (rewritten every call; deterministic).
__device__ __align__(16) float g_Wh3p[32*WSTRIDE];

__global__ __launch_bounds__(256) void pad_wh3_kernel(const float* __restrict__ Wh3){
    int idx = blockIdx.x*256 + threadIdx.x;
    if (idx < 32*WCOLS){
        int k = idx / WCOLS;
        int c = idx - k*WCOLS;
        g_Wh3p[k*WSTRIDE + c] = Wh3[idx];
    }
}

// c_plane [B][C=128][VOX] -> ct [B][VOX][C=128]
__global__ __launch_bounds__(256) void transpose_kernel(const float* __restrict__ in,
                                                        float* __restrict__ out){
    __shared__ float tile[128][33];
    const int blk = blockIdx.x;        // NB * (VOX/32) blocks
    const int b  = blk >> 13;          // VOX/32 = 8192
    const int v0 = (blk & 8191) << 5;  // *32
    const int tx = threadIdx.x & 31;
    const int ty = threadIdx.x >> 5;   // 0..7
    const float* ip = in + (size_t)b*128*VOX + v0;
    #pragma unroll
    for (int cc = 0; cc < 16; cc++){
        int c = cc*8 + ty;
        tile[c][tx] = ip[(size_t)c*VOX + tx];
    }
    __syncthreads();
    const int cx = threadIdx.x & 127;
    const int vy = threadIdx.x >> 7;   // 0..1
    float* op = out + ((size_t)b*VOX + v0)*128;
    #pragma unroll
    for (int vv = 0; vv < 16; vv++){
        int v = vv*2 + vy;
        op[(size_t)v*128 + cx] = tile[cx][v];
    }
}

// wave-per-point trilinear sample from channel-last ct; lane handles 2 channels
__global__ __launch_bounds__(256) void sample_kernel(const float* __restrict__ pcl_mem,
                                                     const float* __restrict__ ct,
                                                     float* __restrict__ feats){
    const int tid  = threadIdx.x;
    const int lane = tid & 63;
    const int p    = blockIdx.x*4 + (tid >> 6);
    const int b    = p >> 16;

    float v0 = pcl_mem[3*p+0], v1 = pcl_mem[3*p+1], v2 = pcl_mem[3*p+2];
    auto src = [](float v){
        float g = 2.0f*v/63.0f - 1.0f;
        g = fminf(fmaxf(g, -2.0f), 2.0f);
        float t = (g + 1.0f)*0.5f*63.0f;
        return fminf(fmaxf(t, 0.0f), 63.0f);
    };
    float ix = src(v0), iy = src(v1), iz = src(v2);
    float fx = floorf(ix), fy = floorf(iy), fz = floorf(iz);
    float wx = ix-fx, wy = iy-fy, wz = iz-fz;
    int x0 = min(max((int)fx,0),63); int x1 = min(x0+1,63);
    int y0 = min(max((int)fy,0),63); int y1 = min(y0+1,63);
    int z0 = min(max((int)fz,0),63); int z1 = min(z0+1,63);
    float wx0 = 1.f-wx, wy0 = 1.f-wy, wz0 = 1.f-wz;

    const float2* base = (const float2*)ct + (size_t)b*VOX*64 + lane;
    float ax = 0.f, ay = 0.f;
#define CORNER(zz,yy,xx,wgt) { \
        float2 cv = base[(size_t)(((zz)*64+(yy))*64+(xx))*64]; \
        float w_ = (wgt); \
        ax = fmaf(w_, cv.x, ax); ay = fmaf(w_, cv.y, ay); }
    CORNER(z0,y0,x0, wz0*wy0*wx0);
    CORNER(z0,y0,x1, wz0*wy0*wx );
    CORNER(z0,y1,x0, wz0*wy *wx0);
    CORNER(z0,y1,x1, wz0*wy *wx );
    CORNER(z1,y0,x0, wz *wy0*wx0);
    CORNER(z1,y0,x1, wz *wy0*wx );
    CORNER(z1,y1,x0, wz *wy *wx0);
    CORNER(z1,y1,x1, wz *wy *wx );
#undef CORNER
    ((float2*)(feats + (size_t)p*CDIM))[lane] = make_float2(ax, ay);
}

// fallback (ws too small): thread per (point, channel), original layout
__global__ __launch_bounds__(256) void sample_slow_kernel(const float* __restrict__ pcl_mem,
                                                          const float* __restrict__ cpl,
                                                          float* __restrict__ feats){
    int gid = blockIdx.x*256 + threadIdx.x;   // p*128 + c
    int p = gid >> 7; int c = gid & 127;
    int b = p >> 16;
    float v0 = pcl_mem[3*p+0], v1 = pcl_mem[3*p+1], v2 = pcl_mem[3*p+2];
    auto src = [](float v){
        float g = 2.0f*v/63.0f - 1.0f;
        g = fminf(fmaxf(g, -2.0f), 2.0f);
        float t = (g + 1.0f)*0.5f*63.0f;
        return fminf(fmaxf(t, 0.0f), 63.0f);
    };
    float ix = src(v0), iy = src(v1), iz = src(v2);
    float fx = floorf(ix), fy = floorf(iy), fz = floorf(iz);
    float wx = ix-fx, wy = iy-fy, wz = iz-fz;
    int x0 = min(max((int)fx,0),63); int x1 = min(x0+1,63);
    int y0 = min(max((int)fy,0),63); int y1 = min(y0+1,63);
    int z0 = min(max((int)fz,0),63); int z1 = min(z0+1,63);
    float wx0 = 1.f-wx, wy0 = 1.f-wy, wz0 = 1.f-wz;
    const float* base = cpl + ((size_t)(b*128 + c))*VOX;
    float acc = 0.f;
    acc = fmaf(wz0*wy0*wx0, base[(z0*64+y0)*64+x0], acc);
    acc = fmaf(wz0*wy0*wx , base[(z0*64+y0)*64+x1], acc);
    acc = fmaf(wz0*wy *wx0, base[(z0*64+y1)*64+x0], acc);
    acc = fmaf(wz0*wy *wx , base[(z0*64+y1)*64+x1], acc);
    acc = fmaf(wz *wy0*wx0, base[(z1*64+y0)*64+x0], acc);
    acc = fmaf(wz *wy0*wx , base[(z1*64+y0)*64+x1], acc);
    acc = fmaf(wz *wy *wx0, base[(z1*64+y1)*64+x0], acc);
    acc = fmaf(wz *wy *wx , base[(z1*64+y1)*64+x1], acc);
    feats[gid] = acc;
}

__device__ __forceinline__ void fma4(float (&acc)[32], int jv, float s, float4 w){
    acc[4*jv+0] = fmaf(s, w.x, acc[4*jv+0]);
    acc[4*jv+1] = fmaf(s, w.y, acc[4*jv+1]);
    acc[4*jv+2] = fmaf(s, w.z, acc[4*jv+2]);
    acc[4*jv+3] = fmaf(s, w.w, acc[4*jv+3]);
}

// ---------------------------------------------------------------------------
// Thread-per-point fused MLP + hypernetwork. ONE-WAVE BLOCKS (64 threads),
// grid = 2048 blocks (work-limited 2 waves/SIMD -> occupancy fixed ~24%).
//
// Round-5 change: LAUNDER the weight base pointers through a "+v" asm so the
// compiler cannot prove them wave-uniform. This moves the weight streams from
// SGPR-buffered s_load (prefetch depth capped by the 112-SGPR file ~= 256 B in
// flight vs ~400 cyc latency -> 23% VALU duty) to VMEM global_load_dwordx4:
// vmcnt queue + the idle VGPR file (68 used of the 256 that our grid-limited
// residency allows) as the pipeline buffer, served by vL1/L2 (8 waves/CU all
// stream the same 158 KB). Addresses are uniform-VALUED -> coalesced to one
// line. Arithmetic untouched -> bit-identical output.
// __launch_bounds__(64,2) caps VGPR at 256: guarantees 2 waves/SIMD, no
// round-1-style spill cliff.
// ---------------------------------------------------------------------------
__global__ __launch_bounds__(64, 2) void mlp_kernel(
        const float* __restrict__ pcl_mem,
        const float* __restrict__ Wh1, const float* __restrict__ bh1,
        const float* __restrict__ Wh2, const float* __restrict__ bh2,
        const float* __restrict__ bh3,
        const float* __restrict__ feats,
        float* __restrict__ outp)
{
    __shared__ float lds_a[32][64];    // h1a -> a1 -> leaky(o2); own column only
    const int tid = threadIdx.x;       // 0..63
    const int p   = blockIdx.x*64 + tid;

    float xv0, xv1, xv2;
    {
        float v0 = pcl_mem[3*p+0], v1 = pcl_mem[3*p+1], v2 = pcl_mem[3*p+2];
        xv0 = v0 - truncf(v0) - 0.5f;
        xv1 = v1 - truncf(v1) - 0.5f;
        xv2 = v2 - truncf(v2) - 0.5f;
    }

    // ---- launder weight pointers into VGPRs: forces VMEM (deep-pipelined)
    // loads instead of SGPR-starved s_load streams. Values are still uniform
    // across lanes -> each load coalesces to a single L1/L2 line.
    uintptr_t w1a = (uintptr_t)Wh1;      asm volatile("" : "+v"(w1a));
    uintptr_t w2a = (uintptr_t)Wh2;      asm volatile("" : "+v"(w2a));
    uintptr_t w3a = (uintptr_t)g_Wh3p;   asm volatile("" : "+v"(w3a));
    uintptr_t b3a = (uintptr_t)bh3;      asm volatile("" : "+v"(b3a));

    const float4* f4  = (const float4*)(feats + (size_t)p*CDIM);
    const float4* W1q = (const float4*)w1a;
    const float4* W2q = (const float4*)w2a;
    const float4* W3q = (const float4*)w3a;
    const float*  W3f = (const float*)w3a;
    const float4* b1q = (const float4*)bh1;
    const float4* b2q = (const float4*)bh2;
    const float4* b3q = (const float4*)b3a;
    const float*  b3f = (const float*)b3a;
    const int RS = WSTRIDE/4;   // 308 float4 per Wh3p row

    // ---- h1 = leaky(feats @ Wh1 + bh1) ----
    float h1[32];
    #pragma unroll
    for (int jv=0;jv<8;jv++){ float4 bv=b1q[jv]; h1[4*jv]=bv.x; h1[4*jv+1]=bv.y; h1[4*jv+2]=bv.z; h1[4*jv+3]=bv.w; }
    for (int c4=0;c4<32;c4++){
        float4 f = f4[c4];
        float fs[4] = {f.x, f.y, f.z, f.w};
        #pragma unroll
        for (int cc=0;cc<4;cc++){
            #pragma unroll
            for (int jv=0;jv<8;jv++)
                fma4(h1, jv, fs[cc], W1q[(c4*4+cc)*8 + jv]);
        }
    }
    #pragma unroll
    for (int j=0;j<32;j++){ float a=h1[j]; lds_a[j][tid] = fmaxf(a, 0.01f*a); }

    // ---- h2 = leaky(h1a @ Wh2 + bh2) ---- (h2a stays in registers only)
    float h2[32];
    #pragma unroll
    for (int kv=0;kv<8;kv++){ float4 bv=b2q[kv]; h2[4*kv]=bv.x; h2[4*kv+1]=bv.y; h2[4*kv+2]=bv.z; h2[4*kv+3]=bv.w; }
    for (int j=0;j<32;j++){
        float aj = lds_a[j][tid];
        #pragma unroll
        for (int kv=0;kv<8;kv++) fma4(h2, kv, aj, W2q[j*8+kv]);
    }
    float h2a[32];
    #pragma unroll
    for (int k=0;k<32;k++){ float a=h2[k]; h2a[k] = fmaxf(a, 0.01f*a); }

    // ---- o1[j] = x . W1'[:, j] + b1'[j], fused from hw cols 0..127.
    // Chunked: 4 chunks of 8 columns; k unrolled (h2a static). Per-element
    // accumulation order identical to the round-0 full-width version.
    #pragma unroll 1
    for (int jc=0;jc<4;jc++){
        float acc[8];
        #pragma unroll
        for (int q=0;q<2;q++){
            float4 ba=b3q[jc*2+q], bb=b3q[8+jc*2+q], bc=b3q[16+jc*2+q], bd=b3q[24+jc*2+q];
            acc[4*q+0] = fmaf(xv0,ba.x, fmaf(xv1,bb.x, fmaf(xv2,bc.x, bd.x)));
            acc[4*q+1] = fmaf(xv0,ba.y, fmaf(xv1,bb.y, fmaf(xv2,bc.y, bd.y)));
            acc[4*q+2] = fmaf(xv0,ba.z, fmaf(xv1,bb.z, fmaf(xv2,bc.z, bd.z)));
            acc[4*q+3] = fmaf(xv0,ba.w, fmaf(xv1,bb.w, fmaf(xv2,bc.w, bd.w)));
        }
        #pragma unroll
        for (int k=0;k<32;k++){
            const float4* row = W3q + (size_t)k*RS + jc*2;
            float hk = h2a[k];
            #pragma unroll
            for (int q=0;q<2;q++){
                float4 wa=row[q], wb=row[8+q], wc=row[16+q], wd=row[24+q];
                acc[4*q+0] = fmaf(hk, fmaf(xv0,wa.x, fmaf(xv1,wb.x, fmaf(xv2,wc.x, wd.x))), acc[4*q+0]);
                acc[4*q+1] = fmaf(hk, fmaf(xv0,wa.y, fmaf(xv1,wb.y, fmaf(xv2,wc.y, wd.y))), acc[4*q+1]);
                acc[4*q+2] = fmaf(hk, fmaf(xv0,wa.z, fmaf(xv1,wb.z, fmaf(xv2,wc.z, wd.z))), acc[4*q+2]);
                acc[4*q+3] = fmaf(hk, fmaf(xv0,wa.w, fmaf(xv1,wb.w, fmaf(xv2,wc.w, wd.w))), acc[4*q+3]);
            }
        }
        #pragma unroll
        for (int r=0;r<8;r++){ float a=acc[r]; lds_a[jc*8+r][tid] = fmaxf(a, 0.01f*a); }  // a1 chunk
    }

    // ---- o2 init = b2' + h2a . W3[:,1152..1183]  (hw cols 1152..1183), k unrolled ----
    float o2[32];
    #pragma unroll
    for (int jv=0;jv<8;jv++){ float4 bv=b3q[288+jv]; o2[4*jv]=bv.x; o2[4*jv+1]=bv.y; o2[4*jv+2]=bv.z; o2[4*jv+3]=bv.w; }
    #pragma unroll
    for (int k=0;k<32;k++){
        const float4* row = W3q + (size_t)k*RS + 288;
        float hk = h2a[k];
        #pragma unroll
        for (int jv=0;jv<8;jv++) fma4(o2, jv, hk, row[jv]);
    }

    // ---- main contraction: o2[j] += sum_i a1[i] * (bh3 + h2.Wh3)[128+i*32+j] ----
    #pragma unroll 1
    for (int i=0;i<32;i++){
        float ai = lds_a[i][tid];
        float w2[32];
        #pragma unroll
        for (int jv=0;jv<8;jv++){ float4 bv=b3q[32+i*8+jv]; w2[4*jv]=bv.x; w2[4*jv+1]=bv.y; w2[4*jv+2]=bv.z; w2[4*jv+3]=bv.w; }
        #pragma unroll
        for (int k=0;k<32;k++){
            const float4* row = W3q + (size_t)k*RS + 32 + i*8;
            #pragma unroll
            for (int jv=0;jv<8;jv++) fma4(w2, jv, h2a[k], row[jv]);
        }
        #pragma unroll
        for (int j=0;j<32;j++) o2[j] = fmaf(ai, w2[j], o2[j]);
    }

    // stash a2 = leaky(o2) in LDS (a1 is dead) for chunked final read-back
    #pragma unroll
    for (int j=0;j<32;j++){ float a=o2[j]; lds_a[j][tid] = fmaxf(a, 0.01f*a); }

    // ---- final: o3 = a2 . W3' + b3'  (hw cols 1184..1216) ----
    float o3 = b3f[1216];
    #pragma unroll
    for (int k=0;k<32;k++) o3 = fmaf(h2a[k], W3f[k*WSTRIDE + 1216], o3);
    #pragma unroll 1
    for (int jc=0;jc<4;jc++){
        float w3c[8];
        #pragma unroll
        for (int q=0;q<2;q++){
            float4 bv=b3q[296+jc*2+q];
            w3c[4*q]=bv.x; w3c[4*q+1]=bv.y; w3c[4*q+2]=bv.z; w3c[4*q+3]=bv.w;
        }
        #pragma unroll
        for (int k=0;k<32;k++){
            const float4* row = W3q + (size_t)k*RS + 296 + jc*2;
            float hk = h2a[k];
            #pragma unroll
            for (int q=0;q<2;q++){
                float4 w=row[q];
                w3c[4*q+0] = fmaf(hk, w.x, w3c[4*q+0]);
                w3c[4*q+1] = fmaf(hk, w.y, w3c[4*q+1]);
                w3c[4*q+2] = fmaf(hk, w.z, w3c[4*q+2]);
                w3c[4*q+3] = fmaf(hk, w.w, w3c[4*q+3]);
            }
        }
        #pragma unroll
        for (int r=0;r<8;r++) o3 = fmaf(lds_a[jc*8+r][tid], w3c[r], o3);
    }

    outp[p] = o3;
}

extern "C" void kernel_launch(void* const* d_in, const int* in_sizes, int n_in,
                              void* d_out, int out_size, void* d_ws, size_t ws_size,
                              hipStream_t stream)
{
    const float* pcl_mem = (const float*)d_in[1];
    const float* c_plane = (const float*)d_in[2];
    const float* Wh1     = (const float*)d_in[3];
    const float* bh1     = (const float*)d_in[4];
    const float* Wh2     = (const float*)d_in[5];
    const float* bh2     = (const float*)d_in[6];
    const float* Wh3     = (const float*)d_in[7];
    const float* bh3     = (const float*)d_in[8];
    float* outp  = (float*)d_out;
    float* feats = outp + NPTS;

    pad_wh3_kernel<<<(32*WCOLS+255)/256, 256, 0, stream>>>(Wh3);

    const size_t ct_bytes = (size_t)NB*VOX*CDIM*sizeof(float);   // 256 MiB
    if (ws_size >= ct_bytes) {
        float* ct = (float*)d_ws;
        transpose_kernel<<<NB*(VOX/32), 256, 0, stream>>>(c_plane, ct);
        sample_kernel<<<NPTS/4, 256, 0, stream>>>(pcl_mem, ct, feats);
    } else {
        sample_slow_kernel<<<(NPTS*CDIM)/256, 256, 0, stream>>>(pcl_mem, c_plane, feats);
    }

    mlp_kernel<<<NPTS/64, 64, 0, stream>>>(pcl_mem, Wh1, bh1, Wh2, bh2, bh3, feats, outp);
}

// Round 6
// 720.984 us; speedup vs baseline: 1.7307x; 1.7307x over previous
//
#include <hip/hip_runtime.h>
#include <cstdint>

#define NB 2
#define NPER 65536
#define NPTS (NB*NPER)
#define CDIM 128
#define SV 64
#define VOX (SV*SV*SV)
#define WCOLS 1217
#define WSTRIDE 1232   // padded row stride in LDS (multiple of 16 floats)

// c_plane [B][C=128][VOX] -> ct [B][VOX][C=128]
__global__ __launch_bounds__(256) void transpose_kernel(const float* __restrict__ in,
                                                        float* __restrict__ out){
    __shared__ float tile[128][33];
    const int blk = blockIdx.x;        // NB * (VOX/32) blocks
    const int b  = blk >> 13;          // VOX/32 = 8192
    const int v0 = (blk & 8191) << 5;  // *32
    const int tx = threadIdx.x & 31;
    const int ty = threadIdx.x >> 5;   // 0..7
    const float* ip = in + (size_t)b*128*VOX + v0;
    #pragma unroll
    for (int cc = 0; cc < 16; cc++){
        int c = cc*8 + ty;
        tile[c][tx] = ip[(size_t)c*VOX + tx];
    }
    __syncthreads();
    const int cx = threadIdx.x & 127;
    const int vy = threadIdx.x >> 7;   // 0..1
    float* op = out + ((size_t)b*VOX + v0)*128;
    #pragma unroll
    for (int vv = 0; vv < 16; vv++){
        int v = vv*2 + vy;
        op[(size_t)v*128 + cx] = tile[cx][v];
    }
}

// wave-per-point trilinear sample from channel-last ct; lane handles 2 channels
__global__ __launch_bounds__(256) void sample_kernel(const float* __restrict__ pcl_mem,
                                                     const float* __restrict__ ct,
                                                     float* __restrict__ feats){
    const int tid  = threadIdx.x;
    const int lane = tid & 63;
    const int p    = blockIdx.x*4 + (tid >> 6);
    const int b    = p >> 16;

    float v0 = pcl_mem[3*p+0], v1 = pcl_mem[3*p+1], v2 = pcl_mem[3*p+2];
    auto src = [](float v){
        float g = 2.0f*v/63.0f - 1.0f;
        g = fminf(fmaxf(g, -2.0f), 2.0f);
        float t = (g + 1.0f)*0.5f*63.0f;
        return fminf(fmaxf(t, 0.0f), 63.0f);
    };
    float ix = src(v0), iy = src(v1), iz = src(v2);
    float fx = floorf(ix), fy = floorf(iy), fz = floorf(iz);
    float wx = ix-fx, wy = iy-fy, wz = iz-fz;
    int x0 = min(max((int)fx,0),63); int x1 = min(x0+1,63);
    int y0 = min(max((int)fy,0),63); int y1 = min(y0+1,63);
    int z0 = min(max((int)fz,0),63); int z1 = min(z0+1,63);
    float wx0 = 1.f-wx, wy0 = 1.f-wy, wz0 = 1.f-wz;

    const float2* base = (const float2*)ct + (size_t)b*VOX*64 + lane;
    float ax = 0.f, ay = 0.f;
#define CORNER(zz,yy,xx,wgt) { \
        float2 cv = base[(size_t)(((zz)*64+(yy))*64+(xx))*64]; \
        float w_ = (wgt); \
        ax = fmaf(w_, cv.x, ax); ay = fmaf(w_, cv.y, ay); }
    CORNER(z0,y0,x0, wz0*wy0*wx0);
    CORNER(z0,y0,x1, wz0*wy0*wx );
    CORNER(z0,y1,x0, wz0*wy *wx0);
    CORNER(z0,y1,x1, wz0*wy *wx );
    CORNER(z1,y0,x0, wz *wy0*wx0);
    CORNER(z1,y0,x1, wz *wy0*wx );
    CORNER(z1,y1,x0, wz *wy *wx0);
    CORNER(z1,y1,x1, wz *wy *wx );
#undef CORNER
    ((float2*)(feats + (size_t)p*CDIM))[lane] = make_float2(ax, ay);
}

// fallback (ws too small): thread per (point, channel), original layout
__global__ __launch_bounds__(256) void sample_slow_kernel(const float* __restrict__ pcl_mem,
                                                          const float* __restrict__ cpl,
                                                          float* __restrict__ feats){
    int gid = blockIdx.x*256 + threadIdx.x;   // p*128 + c
    int p = gid >> 7; int c = gid & 127;
    int b = p >> 16;
    float v0 = pcl_mem[3*p+0], v1 = pcl_mem[3*p+1], v2 = pcl_mem[3*p+2];
    auto src = [](float v){
        float g = 2.0f*v/63.0f - 1.0f;
        g = fminf(fmaxf(g, -2.0f), 2.0f);
        float t = (g + 1.0f)*0.5f*63.0f;
        return fminf(fmaxf(t, 0.0f), 63.0f);
    };
    float ix = src(v0), iy = src(v1), iz = src(v2);
    float fx = floorf(ix), fy = floorf(iy), fz = floorf(iz);
    float wx = ix-fx, wy = iy-fy, wz = iz-fz;
    int x0 = min(max((int)fx,0),63); int x1 = min(x0+1,63);
    int y0 = min(max((int)fy,0),63); int y1 = min(y0+1,63);
    int z0 = min(max((int)fz,0),63); int z1 = min(z0+1,63);
    float wx0 = 1.f-wx, wy0 = 1.f-wy, wz0 = 1.f-wz;
    const float* base = cpl + ((size_t)(b*128 + c))*VOX;
    float acc = 0.f;
    acc = fmaf(wz0*wy0*wx0, base[(z0*64+y0)*64+x0], acc);
    acc = fmaf(wz0*wy0*wx , base[(z0*64+y0)*64+x1], acc);
    acc = fmaf(wz0*wy *wx0, base[(z0*64+y1)*64+x0], acc);
    acc = fmaf(wz0*wy *wx , base[(z0*64+y1)*64+x1], acc);
    acc = fmaf(wz *wy0*wx0, base[(z1*64+y0)*64+x0], acc);
    acc = fmaf(wz *wy0*wx , base[(z1*64+y0)*64+x1], acc);
    acc = fmaf(wz *wy *wx0, base[(z1*64+y1)*64+x0], acc);
    acc = fmaf(wz *wy *wx , base[(z1*64+y1)*64+x1], acc);
    feats[gid] = acc;
}

__device__ __forceinline__ void fma4(float (&acc)[32], int jv, float s, float4 w){
    acc[4*jv+0] = fmaf(s, w.x, acc[4*jv+0]);
    acc[4*jv+1] = fmaf(s, w.y, acc[4*jv+1]);
    acc[4*jv+2] = fmaf(s, w.z, acc[4*jv+2]);
    acc[4*jv+3] = fmaf(s, w.w, acc[4*jv+3]);
}

// ---------------------------------------------------------------------------
// Thread-per-point fused MLP + hypernetwork, Wh3 STAGED IN LDS.
//   block = 512 threads (8 waves), grid = NPTS/512 = 256 = #CUs -> 1 block/CU.
//   LDS = Wh3 padded [32][1232] = 154 KB (fits the 160 KB/CU pool).
// Rationale (rounds 4/5): the per-thread 158 KB Wh3 stream has no cache tier
// that holds it (sL1 16KB, vL1 32KB both thrash -> every read is an L2
// round-trip; 2 waves/SIMD can't hide it -> VALUBusy 23%). LDS holds ALL of
// it at ~120cyc latency; reads are uniform-address broadcasts (conflict-free)
// on the DS pipe, overlapping the VALU FMA stream.
// lds_a bounce is gone: h1a and leaky(o2) consumers are fully unrolled into
// registers (same values, same FMA order); only a1 (runtime i) uses a 128 B
// scratch array (32 st + 32 ld per thread).
// Arithmetic order identical to round 4 -> bit-identical output.
// ---------------------------------------------------------------------------
__global__ __launch_bounds__(512) void mlp_kernel(
        const float* __restrict__ pcl_mem,
        const float* __restrict__ Wh1, const float* __restrict__ bh1,
        const float* __restrict__ Wh2, const float* __restrict__ bh2,
        const float* __restrict__ Wh3, const float* __restrict__ bh3,
        const float* __restrict__ feats,
        float* __restrict__ outp)
{
    __shared__ __align__(16) float W3s[32*WSTRIDE];   // 154 KB
    const int tid = threadIdx.x;       // 0..511
    const int p   = blockIdx.x*512 + tid;

    // cooperative stage: Wh3 [32][1217] -> W3s [32][1232] (padded rows)
    for (int t = tid; t < 32*WCOLS; t += 512){
        int k = t / WCOLS;
        int c = t - k*WCOLS;
        W3s[k*WSTRIDE + c] = Wh3[t];
    }
    __syncthreads();

    float xv0, xv1, xv2;
    {
        float v0 = pcl_mem[3*p+0], v1 = pcl_mem[3*p+1], v2 = pcl_mem[3*p+2];
        xv0 = v0 - truncf(v0) - 0.5f;
        xv1 = v1 - truncf(v1) - 0.5f;
        xv2 = v2 - truncf(v2) - 0.5f;
    }

    const float4* f4  = (const float4*)(feats + (size_t)p*CDIM);
    const float4* W1q = (const float4*)Wh1;
    const float4* W2q = (const float4*)Wh2;
    const float4* b1q = (const float4*)bh1;
    const float4* b2q = (const float4*)bh2;
    const float4* b3q = (const float4*)bh3;

    // ---- h1 = leaky(feats @ Wh1 + bh1) ----
    float h1[32];
    #pragma unroll
    for (int jv=0;jv<8;jv++){ float4 bv=b1q[jv]; h1[4*jv]=bv.x; h1[4*jv+1]=bv.y; h1[4*jv+2]=bv.z; h1[4*jv+3]=bv.w; }
    for (int c4=0;c4<32;c4++){
        float4 f = f4[c4];
        float fs[4] = {f.x, f.y, f.z, f.w};
        #pragma unroll
        for (int cc=0;cc<4;cc++){
            #pragma unroll
            for (int jv=0;jv<8;jv++)
                fma4(h1, jv, fs[cc], W1q[(c4*4+cc)*8 + jv]);
        }
    }
    float ha[32];   // h1a in registers (was LDS bounce)
    #pragma unroll
    for (int j=0;j<32;j++){ float a=h1[j]; ha[j] = fmaxf(a, 0.01f*a); }

    // ---- h2 = leaky(h1a @ Wh2 + bh2), j fully unrolled (ha static) ----
    float h2[32];
    #pragma unroll
    for (int kv=0;kv<8;kv++){ float4 bv=b2q[kv]; h2[4*kv]=bv.x; h2[4*kv+1]=bv.y; h2[4*kv+2]=bv.z; h2[4*kv+3]=bv.w; }
    #pragma unroll
    for (int j=0;j<32;j++){
        float aj = ha[j];
        #pragma unroll
        for (int kv=0;kv<8;kv++) fma4(h2, kv, aj, W2q[j*8+kv]);
    }
    float h2a[32];
    #pragma unroll
    for (int k=0;k<32;k++){ float a=h2[k]; h2a[k] = fmaxf(a, 0.01f*a); }

    // ---- o1[j] = x . W1'[:, j] + b1'[j] (hw cols 0..127), weights from LDS.
    // a1 goes to a tiny scratch array (runtime-indexed later).
    float a1s[32];
    #pragma unroll 1
    for (int jc=0;jc<4;jc++){
        float acc[8];
        #pragma unroll
        for (int q=0;q<2;q++){
            float4 ba=b3q[jc*2+q], bb=b3q[8+jc*2+q], bc=b3q[16+jc*2+q], bd=b3q[24+jc*2+q];
            acc[4*q+0] = fmaf(xv0,ba.x, fmaf(xv1,bb.x, fmaf(xv2,bc.x, bd.x)));
            acc[4*q+1] = fmaf(xv0,ba.y, fmaf(xv1,bb.y, fmaf(xv2,bc.y, bd.y)));
            acc[4*q+2] = fmaf(xv0,ba.z, fmaf(xv1,bb.z, fmaf(xv2,bc.z, bd.z)));
            acc[4*q+3] = fmaf(xv0,ba.w, fmaf(xv1,bb.w, fmaf(xv2,bc.w, bd.w)));
        }
        #pragma unroll
        for (int k=0;k<32;k++){
            const float4* row = (const float4*)(W3s + k*WSTRIDE) + jc*2;
            float hk = h2a[k];
            #pragma unroll
            for (int q=0;q<2;q++){
                float4 wa=row[q], wb=row[8+q], wc=row[16+q], wd=row[24+q];
                acc[4*q+0] = fmaf(hk, fmaf(xv0,wa.x, fmaf(xv1,wb.x, fmaf(xv2,wc.x, wd.x))), acc[4*q+0]);
                acc[4*q+1] = fmaf(hk, fmaf(xv0,wa.y, fmaf(xv1,wb.y, fmaf(xv2,wc.y, wd.y))), acc[4*q+1]);
                acc[4*q+2] = fmaf(hk, fmaf(xv0,wa.z, fmaf(xv1,wb.z, fmaf(xv2,wc.z, wd.z))), acc[4*q+2]);
                acc[4*q+3] = fmaf(hk, fmaf(xv0,wa.w, fmaf(xv1,wb.w, fmaf(xv2,wc.w, wd.w))), acc[4*q+3]);
            }
        }
        #pragma unroll
        for (int r=0;r<8;r++){ float a=acc[r]; a1s[jc*8+r] = fmaxf(a, 0.01f*a); }
    }

    // ---- o2 init = b2' + h2a . W3[:,1152..1183] (LDS), k unrolled ----
    float o2[32];
    #pragma unroll
    for (int jv=0;jv<8;jv++){ float4 bv=b3q[288+jv]; o2[4*jv]=bv.x; o2[4*jv+1]=bv.y; o2[4*jv+2]=bv.z; o2[4*jv+3]=bv.w; }
    #pragma unroll
    for (int k=0;k<32;k++){
        const float4* row = (const float4*)(W3s + k*WSTRIDE) + 288;
        float hk = h2a[k];
        #pragma unroll
        for (int jv=0;jv<8;jv++) fma4(o2, jv, hk, row[jv]);
    }

    // ---- main contraction: o2[j] += sum_i a1[i] * (bh3 + h2.Wh3)[128+i*32+j] ----
    #pragma unroll 1
    for (int i=0;i<32;i++){
        float ai = a1s[i];
        float w2[32];
        #pragma unroll
        for (int jv=0;jv<8;jv++){ float4 bv=b3q[32+i*8+jv]; w2[4*jv]=bv.x; w2[4*jv+1]=bv.y; w2[4*jv+2]=bv.z; w2[4*jv+3]=bv.w; }
        #pragma unroll
        for (int k=0;k<32;k++){
            const float4* row = (const float4*)(W3s + k*WSTRIDE) + 32 + i*8;
            #pragma unroll
            for (int jv=0;jv<8;jv++) fma4(w2, jv, h2a[k], row[jv]);
        }
        #pragma unroll
        for (int j=0;j<32;j++) o2[j] = fmaf(ai, w2[j], o2[j]);
    }

    // a2 = leaky(o2) in registers (consumer fully unrolled below)
    float a2r[32];
    #pragma unroll
    for (int j=0;j<32;j++){ float a=o2[j]; a2r[j] = fmaxf(a, 0.01f*a); }

    // ---- final: o3 = a2 . W3' + b3' (hw cols 1184..1216), jc fully unrolled ----
    float o3 = bh3[1216];
    #pragma unroll
    for (int k=0;k<32;k++) o3 = fmaf(h2a[k], W3s[k*WSTRIDE + 1216], o3);
    #pragma unroll
    for (int jc=0;jc<4;jc++){
        float w3c[8];
        #pragma unroll
        for (int q=0;q<2;q++){
            float4 bv=b3q[296+jc*2+q];
            w3c[4*q]=bv.x; w3c[4*q+1]=bv.y; w3c[4*q+2]=bv.z; w3c[4*q+3]=bv.w;
        }
        #pragma unroll
        for (int k=0;k<32;k++){
            const float4* row = (const float4*)(W3s + k*WSTRIDE) + 296 + jc*2;
            float hk = h2a[k];
            #pragma unroll
            for (int q=0;q<2;q++){
                float4 w=row[q];
                w3c[4*q+0] = fmaf(hk, w.x, w3c[4*q+0]);
                w3c[4*q+1] = fmaf(hk, w.y, w3c[4*q+1]);
                w3c[4*q+2] = fmaf(hk, w.z, w3c[4*q+2]);
                w3c[4*q+3] = fmaf(hk, w.w, w3c[4*q+3]);
            }
        }
        #pragma unroll
        for (int r=0;r<8;r++) o3 = fmaf(a2r[jc*8+r], w3c[r], o3);
    }

    outp[p] = o3;
}

extern "C" void kernel_launch(void* const* d_in, const int* in_sizes, int n_in,
                              void* d_out, int out_size, void* d_ws, size_t ws_size,
                              hipStream_t stream)
{
    const float* pcl_mem = (const float*)d_in[1];
    const float* c_plane = (const float*)d_in[2];
    const float* Wh1     = (const float*)d_in[3];
    const float* bh1     = (const float*)d_in[4];
    const float* Wh2     = (const float*)d_in[5];
    const float* bh2     = (const float*)d_in[6];
    const float* Wh3     = (const float*)d_in[7];
    const float* bh3     = (const float*)d_in[8];
    float* outp  = (float*)d_out;
    float* feats = outp + NPTS;

    const size_t ct_bytes = (size_t)NB*VOX*CDIM*sizeof(float);   // 256 MiB
    if (ws_size >= ct_bytes) {
        float* ct = (float*)d_ws;
        transpose_kernel<<<NB*(VOX/32), 256, 0, stream>>>(c_plane, ct);
        sample_kernel<<<NPTS/4, 256, 0, stream>>>(pcl_mem, ct, feats);
    } else {
        sample_slow_kernel<<<(NPTS*CDIM)/256, 256, 0, stream>>>(pcl_mem, c_plane, feats);
    }

    mlp_kernel<<<NPTS/512, 512, 0, stream>>>(pcl_mem, Wh1, bh1, Wh2, bh2, Wh3, bh3, feats, outp);
}

// Round 7
// 715.775 us; speedup vs baseline: 1.7433x; 1.0073x over previous
//
#include <hip/hip_runtime.h>
#include <cstdint>

#define NB 2
#define NPER 65536
#define NPTS (NB*NPER)
#define CDIM 128
#define SV 64
#define VOX (SV*SV*SV)
#define WCOLS 1217
#define WSTRIDE 1232   // padded row stride in LDS (multiple of 16 floats)

typedef float f2 __attribute__((ext_vector_type(2)));

__device__ __forceinline__ f2 mk2(float a, float b){ f2 r; r.x=a; r.y=b; return r; }
__device__ __forceinline__ f2 pkfma(f2 a, f2 b, f2 c){
#if __has_builtin(__builtin_elementwise_fma)
    return __builtin_elementwise_fma(a, b, c);
#else
    f2 r; r.x = fmaf(a.x, b.x, c.x); r.y = fmaf(a.y, b.y, c.y); return r;
#endif
}

// c_plane [B][C=128][VOX] -> ct [B][VOX][C=128]
__global__ __launch_bounds__(256) void transpose_kernel(const float* __restrict__ in,
                                                        float* __restrict__ out){
    __shared__ float tile[128][33];
    const int blk = blockIdx.x;        // NB * (VOX/32) blocks
    const int b  = blk >> 13;          // VOX/32 = 8192
    const int v0 = (blk & 8191) << 5;  // *32
    const int tx = threadIdx.x & 31;
    const int ty = threadIdx.x >> 5;   // 0..7
    const float* ip = in + (size_t)b*128*VOX + v0;
    #pragma unroll
    for (int cc = 0; cc < 16; cc++){
        int c = cc*8 + ty;
        tile[c][tx] = ip[(size_t)c*VOX + tx];
    }
    __syncthreads();
    const int cx = threadIdx.x & 127;
    const int vy = threadIdx.x >> 7;   // 0..1
    float* op = out + ((size_t)b*VOX + v0)*128;
    #pragma unroll
    for (int vv = 0; vv < 16; vv++){
        int v = vv*2 + vy;
        op[(size_t)v*128 + cx] = tile[cx][v];
    }
}

// wave-per-point trilinear sample from channel-last ct; lane handles 2 channels
__global__ __launch_bounds__(256) void sample_kernel(const float* __restrict__ pcl_mem,
                                                     const float* __restrict__ ct,
                                                     float* __restrict__ feats){
    const int tid  = threadIdx.x;
    const int lane = tid & 63;
    const int p    = blockIdx.x*4 + (tid >> 6);
    const int b    = p >> 16;

    float v0 = pcl_mem[3*p+0], v1 = pcl_mem[3*p+1], v2 = pcl_mem[3*p+2];
    auto src = [](float v){
        float g = 2.0f*v/63.0f - 1.0f;
        g = fminf(fmaxf(g, -2.0f), 2.0f);
        float t = (g + 1.0f)*0.5f*63.0f;
        return fminf(fmaxf(t, 0.0f), 63.0f);
    };
    float ix = src(v0), iy = src(v1), iz = src(v2);
    float fx = floorf(ix), fy = floorf(iy), fz = floorf(iz);
    float wx = ix-fx, wy = iy-fy, wz = iz-fz;
    int x0 = min(max((int)fx,0),63); int x1 = min(x0+1,63);
    int y0 = min(max((int)fy,0),63); int y1 = min(y0+1,63);
    int z0 = min(max((int)fz,0),63); int z1 = min(z0+1,63);
    float wx0 = 1.f-wx, wy0 = 1.f-wy, wz0 = 1.f-wz;

    const float2* base = (const float2*)ct + (size_t)b*VOX*64 + lane;
    float ax = 0.f, ay = 0.f;
#define CORNER(zz,yy,xx,wgt) { \
        float2 cv = base[(size_t)(((zz)*64+(yy))*64+(xx))*64]; \
        float w_ = (wgt); \
        ax = fmaf(w_, cv.x, ax); ay = fmaf(w_, cv.y, ay); }
    CORNER(z0,y0,x0, wz0*wy0*wx0);
    CORNER(z0,y0,x1, wz0*wy0*wx );
    CORNER(z0,y1,x0, wz0*wy *wx0);
    CORNER(z0,y1,x1, wz0*wy *wx );
    CORNER(z1,y0,x0, wz *wy0*wx0);
    CORNER(z1,y0,x1, wz *wy0*wx );
    CORNER(z1,y1,x0, wz *wy *wx0);
    CORNER(z1,y1,x1, wz *wy *wx );
#undef CORNER
    ((float2*)(feats + (size_t)p*CDIM))[lane] = make_float2(ax, ay);
}

// fallback (ws too small): thread per (point, channel), original layout
__global__ __launch_bounds__(256) void sample_slow_kernel(const float* __restrict__ pcl_mem,
                                                          const float* __restrict__ cpl,
                                                          float* __restrict__ feats){
    int gid = blockIdx.x*256 + threadIdx.x;   // p*128 + c
    int p = gid >> 7; int c = gid & 127;
    int b = p >> 16;
    float v0 = pcl_mem[3*p+0], v1 = pcl_mem[3*p+1], v2 = pcl_mem[3*p+2];
    auto src = [](float v){
        float g = 2.0f*v/63.0f - 1.0f;
        g = fminf(fmaxf(g, -2.0f), 2.0f);
        float t = (g + 1.0f)*0.5f*63.0f;
        return fminf(fmaxf(t, 0.0f), 63.0f);
    };
    float ix = src(v0), iy = src(v1), iz = src(v2);
    float fx = floorf(ix), fy = floorf(iy), fz = floorf(iz);
    float wx = ix-fx, wy = iy-fy, wz = iz-fz;
    int x0 = min(max((int)fx,0),63); int x1 = min(x0+1,63);
    int y0 = min(max((int)fy,0),63); int y1 = min(y0+1,63);
    int z0 = min(max((int)fz,0),63); int z1 = min(z0+1,63);
    float wx0 = 1.f-wx, wy0 = 1.f-wy, wz0 = 1.f-wz;
    const float* base = cpl + ((size_t)(b*128 + c))*VOX;
    float acc = 0.f;
    acc = fmaf(wz0*wy0*wx0, base[(z0*64+y0)*64+x0], acc);
    acc = fmaf(wz0*wy0*wx , base[(z0*64+y0)*64+x1], acc);
    acc = fmaf(wz0*wy *wx0, base[(z0*64+y1)*64+x0], acc);
    acc = fmaf(wz0*wy *wx , base[(z0*64+y1)*64+x1], acc);
    acc = fmaf(wz *wy0*wx0, base[(z1*64+y0)*64+x0], acc);
    acc = fmaf(wz *wy0*wx , base[(z1*64+y0)*64+x1], acc);
    acc = fmaf(wz *wy *wx0, base[(z1*64+y1)*64+x0], acc);
    acc = fmaf(wz *wy *wx , base[(z1*64+y1)*64+x1], acc);
    feats[gid] = acc;
}

// ---------------------------------------------------------------------------
// Thread-per-point fused MLP + hypernetwork, Wh3 in LDS (154 KB, 512 thr/blk,
// grid=256 -> 1 block/CU, 8 waves/CU). Round-7 changes vs round 6:
//  (1) NO scratch: a1 lives in registers. The o1 jc-loop is fully unrolled
//      (static writes) and the main contraction consumes a1r[0] with a static
//      31-element rotation per iteration (all indices compile-time ->
//      mem2reg keeps it in VGPRs; was 22 MB of scratch spill).
//  (2) Packed math: accumulators are float2 ext-vectors fed by pkfma ->
//      v_pk_fma_f32 (2 f32 lanes/instr) where the backend selects it.
//      Each output element keeps the exact same FMA chain/order as rounds
//      0/4/6 -> bit-identical output.
// ---------------------------------------------------------------------------
__global__ __launch_bounds__(512) void mlp_kernel(
        const float* __restrict__ pcl_mem,
        const float* __restrict__ Wh1, const float* __restrict__ bh1,
        const float* __restrict__ Wh2, const float* __restrict__ bh2,
        const float* __restrict__ Wh3, const float* __restrict__ bh3,
        const float* __restrict__ feats,
        float* __restrict__ outp)
{
    __shared__ __align__(16) float W3s[32*WSTRIDE];   // 154 KB
    const int tid = threadIdx.x;       // 0..511
    const int p   = blockIdx.x*512 + tid;

    // cooperative stage: Wh3 [32][1217] -> W3s [32][1232] (padded rows)
    for (int t = tid; t < 32*WCOLS; t += 512){
        int k = t / WCOLS;
        int c = t - k*WCOLS;
        W3s[k*WSTRIDE + c] = Wh3[t];
    }
    __syncthreads();

    float xv0, xv1, xv2;
    {
        float v0 = pcl_mem[3*p+0], v1 = pcl_mem[3*p+1], v2 = pcl_mem[3*p+2];
        xv0 = v0 - truncf(v0) - 0.5f;
        xv1 = v1 - truncf(v1) - 0.5f;
        xv2 = v2 - truncf(v2) - 0.5f;
    }

    const float4* f4  = (const float4*)(feats + (size_t)p*CDIM);
    const float4* W1q = (const float4*)Wh1;
    const float4* W2q = (const float4*)Wh2;
    const float4* b1q = (const float4*)bh1;
    const float4* b2q = (const float4*)bh2;
    const float4* b3q = (const float4*)bh3;

    // ---- h1 = leaky(feats @ Wh1 + bh1), packed pairs ----
    f2 h1v[16];
    #pragma unroll
    for (int jv=0;jv<8;jv++){ float4 bv=b1q[jv]; h1v[2*jv]=mk2(bv.x,bv.y); h1v[2*jv+1]=mk2(bv.z,bv.w); }
    for (int c4=0;c4<32;c4++){
        float4 f = f4[c4];
        float fs[4] = {f.x, f.y, f.z, f.w};
        #pragma unroll
        for (int cc=0;cc<4;cc++){
            f2 fc = mk2(fs[cc], fs[cc]);
            #pragma unroll
            for (int jv=0;jv<8;jv++){
                float4 w = W1q[(c4*4+cc)*8 + jv];
                h1v[2*jv]   = pkfma(fc, mk2(w.x,w.y), h1v[2*jv]);
                h1v[2*jv+1] = pkfma(fc, mk2(w.z,w.w), h1v[2*jv+1]);
            }
        }
    }
    float ha[32];
    #pragma unroll
    for (int t=0;t<16;t++){
        float a0=h1v[t].x, a1=h1v[t].y;
        ha[2*t]   = fmaxf(a0, 0.01f*a0);
        ha[2*t+1] = fmaxf(a1, 0.01f*a1);
    }

    // ---- h2 = leaky(h1a @ Wh2 + bh2), j fully unrolled ----
    f2 h2v[16];
    #pragma unroll
    for (int kv=0;kv<8;kv++){ float4 bv=b2q[kv]; h2v[2*kv]=mk2(bv.x,bv.y); h2v[2*kv+1]=mk2(bv.z,bv.w); }
    #pragma unroll
    for (int j=0;j<32;j++){
        f2 aj = mk2(ha[j], ha[j]);
        #pragma unroll
        for (int kv=0;kv<8;kv++){
            float4 w = W2q[j*8+kv];
            h2v[2*kv]   = pkfma(aj, mk2(w.x,w.y), h2v[2*kv]);
            h2v[2*kv+1] = pkfma(aj, mk2(w.z,w.w), h2v[2*kv+1]);
        }
    }
    float h2a[32];
    #pragma unroll
    for (int t=0;t<16;t++){
        float a0=h2v[t].x, a1=h2v[t].y;
        h2a[2*t]   = fmaxf(a0, 0.01f*a0);
        h2a[2*t+1] = fmaxf(a1, 0.01f*a1);
    }

    const f2 x0 = mk2(xv0,xv0), x1 = mk2(xv1,xv1), x2 = mk2(xv2,xv2);

    // ---- o1[j] = x . W1'[:,j] + b1'[j] (hw cols 0..127), weights from LDS.
    // jc fully unrolled -> a1r writes are static -> stays in registers.
    float a1r[32];
    #pragma unroll
    for (int jc=0;jc<4;jc++){
        f2 accv[4];
        #pragma unroll
        for (int q=0;q<2;q++){
            float4 ba=b3q[jc*2+q], bb=b3q[8+jc*2+q], bc=b3q[16+jc*2+q], bd=b3q[24+jc*2+q];
            accv[2*q]   = pkfma(x0,mk2(ba.x,ba.y), pkfma(x1,mk2(bb.x,bb.y), pkfma(x2,mk2(bc.x,bc.y), mk2(bd.x,bd.y))));
            accv[2*q+1] = pkfma(x0,mk2(ba.z,ba.w), pkfma(x1,mk2(bb.z,bb.w), pkfma(x2,mk2(bc.z,bc.w), mk2(bd.z,bd.w))));
        }
        #pragma unroll
        for (int k=0;k<32;k++){
            const float4* row = (const float4*)(W3s + k*WSTRIDE) + jc*2;
            f2 hk = mk2(h2a[k], h2a[k]);
            #pragma unroll
            for (int q=0;q<2;q++){
                float4 wa=row[q], wb=row[8+q], wc=row[16+q], wd=row[24+q];
                f2 m0 = pkfma(x0,mk2(wa.x,wa.y), pkfma(x1,mk2(wb.x,wb.y), pkfma(x2,mk2(wc.x,wc.y), mk2(wd.x,wd.y))));
                f2 m1 = pkfma(x0,mk2(wa.z,wa.w), pkfma(x1,mk2(wb.z,wb.w), pkfma(x2,mk2(wc.z,wc.w), mk2(wd.z,wd.w))));
                accv[2*q]   = pkfma(hk, m0, accv[2*q]);
                accv[2*q+1] = pkfma(hk, m1, accv[2*q+1]);
            }
        }
        #pragma unroll
        for (int q=0;q<2;q++){
            float a0=accv[2*q].x, a1=accv[2*q].y, a2=accv[2*q+1].x, a3=accv[2*q+1].y;
            a1r[jc*8+4*q+0] = fmaxf(a0, 0.01f*a0);
            a1r[jc*8+4*q+1] = fmaxf(a1, 0.01f*a1);
            a1r[jc*8+4*q+2] = fmaxf(a2, 0.01f*a2);
            a1r[jc*8+4*q+3] = fmaxf(a3, 0.01f*a3);
        }
    }

    // ---- o2 init = b2' + h2a . W3[:,1152..1183], k unrolled ----
    f2 o2v[16];
    #pragma unroll
    for (int jv=0;jv<8;jv++){ float4 bv=b3q[288+jv]; o2v[2*jv]=mk2(bv.x,bv.y); o2v[2*jv+1]=mk2(bv.z,bv.w); }
    #pragma unroll
    for (int k=0;k<32;k++){
        const float4* row = (const float4*)(W3s + k*WSTRIDE) + 288;
        f2 hk = mk2(h2a[k], h2a[k]);
        #pragma unroll
        for (int jv=0;jv<8;jv++){
            float4 w = row[jv];
            o2v[2*jv]   = pkfma(hk, mk2(w.x,w.y), o2v[2*jv]);
            o2v[2*jv+1] = pkfma(hk, mk2(w.z,w.w), o2v[2*jv+1]);
        }
    }

    // ---- main contraction: o2[j] += sum_i a1[i]*(bh3 + h2.Wh3)[128+i*32+j].
    // a1 consumed head-first with a STATIC rotation (keeps it in VGPRs).
    #pragma unroll 1
    for (int i=0;i<32;i++){
        f2 ai = mk2(a1r[0], a1r[0]);
        f2 w2v[16];
        #pragma unroll
        for (int jv=0;jv<8;jv++){ float4 bv=b3q[32+i*8+jv]; w2v[2*jv]=mk2(bv.x,bv.y); w2v[2*jv+1]=mk2(bv.z,bv.w); }
        #pragma unroll
        for (int k=0;k<32;k++){
            const float4* row = (const float4*)(W3s + k*WSTRIDE) + 32 + i*8;
            f2 hk = mk2(h2a[k], h2a[k]);
            #pragma unroll
            for (int jv=0;jv<8;jv++){
                float4 w = row[jv];
                w2v[2*jv]   = pkfma(hk, mk2(w.x,w.y), w2v[2*jv]);
                w2v[2*jv+1] = pkfma(hk, mk2(w.z,w.w), w2v[2*jv+1]);
            }
        }
        #pragma unroll
        for (int t=0;t<16;t++) o2v[t] = pkfma(ai, w2v[t], o2v[t]);
        #pragma unroll
        for (int t=0;t<31;t++) a1r[t] = a1r[t+1];
    }

    // a2 = leaky(o2) in registers
    float a2r[32];
    #pragma unroll
    for (int t=0;t<16;t++){
        float a0=o2v[t].x, a1=o2v[t].y;
        a2r[2*t]   = fmaxf(a0, 0.01f*a0);
        a2r[2*t+1] = fmaxf(a1, 0.01f*a1);
    }

    // ---- final: o3 = a2 . W3' + b3' (hw cols 1184..1216) ----
    float o3 = bh3[1216];
    #pragma unroll
    for (int k=0;k<32;k++) o3 = fmaf(h2a[k], W3s[k*WSTRIDE + 1216], o3);
    #pragma unroll
    for (int jc=0;jc<4;jc++){
        float w3c[8];
        #pragma unroll
        for (int q=0;q<2;q++){
            float4 bv=b3q[296+jc*2+q];
            w3c[4*q]=bv.x; w3c[4*q+1]=bv.y; w3c[4*q+2]=bv.z; w3c[4*q+3]=bv.w;
        }
        #pragma unroll
        for (int k=0;k<32;k++){
            const float4* row = (const float4*)(W3s + k*WSTRIDE) + 296 + jc*2;
            float hk = h2a[k];
            #pragma unroll
            for (int q=0;q<2;q++){
                float4 w=row[q];
                w3c[4*q+0] = fmaf(hk, w.x, w3c[4*q+0]);
                w3c[4*q+1] = fmaf(hk, w.y, w3c[4*q+1]);
                w3c[4*q+2] = fmaf(hk, w.z, w3c[4*q+2]);
                w3c[4*q+3] = fmaf(hk, w.w, w3c[4*q+3]);
            }
        }
        #pragma unroll
        for (int r=0;r<8;r++) o3 = fmaf(a2r[jc*8+r], w3c[r], o3);
    }

    outp[p] = o3;
}

extern "C" void kernel_launch(void* const* d_in, const int* in_sizes, int n_in,
                              void* d_out, int out_size, void* d_ws, size_t ws_size,
                              hipStream_t stream)
{
    const float* pcl_mem = (const float*)d_in[1];
    const float* c_plane = (const float*)d_in[2];
    const float* Wh1     = (const float*)d_in[3];
    const float* bh1     = (const float*)d_in[4];
    const float* Wh2     = (const float*)d_in[5];
    const float* bh2     = (const float*)d_in[6];
    const float* Wh3     = (const float*)d_in[7];
    const float* bh3     = (const float*)d_in[8];
    float* outp  = (float*)d_out;
    float* feats = outp + NPTS;

    const size_t ct_bytes = (size_t)NB*VOX*CDIM*sizeof(float);   // 256 MiB
    if (ws_size >= ct_bytes) {
        float* ct = (float*)d_ws;
        transpose_kernel<<<NB*(VOX/32), 256, 0, stream>>>(c_plane, ct);
        sample_kernel<<<NPTS/4, 256, 0, stream>>>(pcl_mem, ct, feats);
    } else {
        sample_slow_kernel<<<(NPTS*CDIM)/256, 256, 0, stream>>>(pcl_mem, c_plane, feats);
    }

    mlp_kernel<<<NPTS/512, 512, 0, stream>>>(pcl_mem, Wh1, bh1, Wh2, bh2, Wh3, bh3, feats, outp);
}